// Round 21
// baseline (102.715 us; speedup 1.0000x reference)
//
#include <hip/hip_runtime.h>

#define N_PTS 32768
#define M_Q   8192
#define C_F   256
#define GS    32
#define NC    (GS * GS * GS)          // 32768 cells per side
#define TOTP  (2 * N_PTS)             // 65536 points
#define TOTQ  (2 * M_Q)               // 16384 queries
#define LOC   (-4.4f)
#define CWID  (8.8f / GS)             // 0.275
#define INVW  (GS / 8.8f)
#define MARG  2e-4f
#define INF_F __int_as_float(0x7f800000)
#define MAXI  0x7fffffff

__device__ __forceinline__ float rn_mul(float a, float b) { return __fmul_rn(a, b); }
__device__ __forceinline__ float rn_add(float a, float b) { return __fadd_rn(a, b); }

__device__ __forceinline__ int cellco(float v) {
    int c = (int)floorf((v - LOC) * INVW);
    return c < 0 ? 0 : (c > GS - 1 ? GS - 1 : c);
}

// exact lexicographic (d,i) insert into running top-2 pair
__device__ __forceinline__ void ins_lex(float d, int i, float& b1, int& j1,
                                        float& b2, int& j2) {
    bool lt1 = (d < b1) || (d == b1 && i < j1);
    bool lt2 = (d < b2) || (d == b2 && i < j2);
    b2 = lt1 ? b1 : (lt2 ? d : b2);
    j2 = lt1 ? j1 : (lt2 ? i : j2);
    b1 = lt1 ? d : b1;
    j1 = lt1 ? i : j1;
}
__device__ __forceinline__ void ins_lex2(float d, int i, float& b2, int& j2) {
    bool lt2 = (d < b2) || (d == b2 && i < j2);
    b2 = lt2 ? d : b2;
    j2 = lt2 ? i : j2;
}

// merge two sorted value-pairs -> two smallest values (multiset-exact)
__device__ __forceinline__ void vpair_merge(float& a1, float& a2, float b1, float b2) {
    float n1 = fminf(a1, b1);
    float n2 = fminf(fmaxf(a1, b1), fminf(a2, b2));
    a1 = n1; a2 = n2;
}

// K1: per-point cell id + histogram
__global__ __launch_bounds__(256) void build_cells(
    const float* __restrict__ c0, const float* __restrict__ c1,
    int* __restrict__ counts, int* __restrict__ cid)
{
    int t = blockIdx.x * 256 + threadIdx.x;     // 0..65535
    int side = t >> 15, n = t & (N_PTS - 1);
    const float* c = side ? c1 : c0;
    float x = c[n * 3], y = c[n * 3 + 1], z = c[n * 3 + 2];
    int g = side * NC + (cellco(z) * GS + cellco(y)) * GS + cellco(x);
    cid[t] = g;
    atomicAdd(&counts[g], 1);
}

// K2: per-256-block exclusive scan, emit block sums
__global__ __launch_bounds__(256) void scan1(const int* __restrict__ counts,
                                             int* __restrict__ starts,
                                             int* __restrict__ bsum)
{
    __shared__ int s[256];
    int b = blockIdx.x, tid = threadIdx.x;
    int v = counts[b * 256 + tid];
    s[tid] = v;
    __syncthreads();
    for (int o = 1; o < 256; o <<= 1) {
        int u = (tid >= o) ? s[tid - o] : 0;
        __syncthreads();
        s[tid] += u;
        __syncthreads();
    }
    starts[b * 256 + tid] = s[tid] - v;   // exclusive
    if (tid == 255) bsum[b] = s[255];
}

// K3: fused scan2+scan3 — each block locally scans the 256 block sums,
// takes its own exclusive prefix, adds to its starts slice.
__global__ __launch_bounds__(256) void scan23(int* __restrict__ starts,
                                              const int* __restrict__ bsum)
{
    __shared__ int s[256];
    int b = blockIdx.x, tid = threadIdx.x;
    int v = bsum[tid];
    s[tid] = v;
    __syncthreads();
    for (int o = 1; o < 256; o <<= 1) {
        int u = (tid >= o) ? s[tid - o] : 0;
        __syncthreads();
        s[tid] += u;
        __syncthreads();
    }
    int off = s[b] - bsum[b];             // exclusive prefix of bsum at b
    starts[b * 256 + tid] += off;
    if (b == 0 && tid == 0) starts[TOTP] = TOTP;   // sentinel
}

// K5: scatter points into cell-sorted pool; index packed into .w (raw bits)
__global__ __launch_bounds__(256) void scatter(
    const float* __restrict__ c0, const float* __restrict__ c1,
    const int* __restrict__ cid, const int* __restrict__ starts,
    int* __restrict__ counts, float4* __restrict__ pts4)
{
    int t = blockIdx.x * 256 + threadIdx.x;
    int side = t >> 15, n = t & (N_PTS - 1);
    const float* c = side ? c1 : c0;
    float x = c[n * 3], y = c[n * 3 + 1], z = c[n * 3 + 2];
    int g = cid[t];
    int pos = starts[g] + (atomicSub(&counts[g], 1) - 1);
    pts4[pos] = make_float4(x, y, z, __int_as_float(n));
}

// K6: one WAVE per query; 2 independent waves per 128-thread block.
// Query-centered boxes, ROW-parallel scanning (rows x-contiguous -> one
// starts-pair per row). Analytic density-adaptive R0 = 0.13*exp(a2/6) (pure
// VALU — no density-probe latency round). Point index rides in pts4.w; b2 is
// recomputed with the exact numpy chain (bit-identical dd). Nested boxes +
// row x-subrange skip => exactly-once. Value-only stop; one lex butterfly.
__global__ __launch_bounds__(128) void query2nn(
    const float* __restrict__ src, const float* __restrict__ tgt,
    const float* __restrict__ sc0, const float* __restrict__ sc1,
    const float4* __restrict__ pts4, const int* __restrict__ starts,
    float* __restrict__ out)
{
    int lane = threadIdx.x & 63;
    int wv   = threadIdx.x >> 6;
    int qid  = blockIdx.x * 2 + wv;          // 0..16383
    int side = qid >> 13, q = qid & (M_Q - 1);
    const float* sc = side ? sc1 : sc0;

    float ax = sc[q * 3], ay = sc[q * 3 + 1], az = sc[q * 3 + 2];
    float a2 = rn_add(rn_add(rn_mul(ax, ax), rn_mul(ay, ay)), rn_mul(az, az));
    const int* st = starts + side * NC;

    float d1 = INF_F, d2 = INF_F;            // per-lane privates (disjoint pts)
    int   i1 = MAXI,  i2 = MAXI;

    // scan points [s0+sub, s1) stride `step`, 2-deep prefetch; ONE load stream
    auto scan_range = [&](int s0, int s1, int sub, int step) {
        int j = s0 + sub;
        if (j >= s1) return;
        float4 p = pts4[j];
        for (j += step; j < s1; j += step) {
            float4 pn = pts4[j];
            float b2 = rn_add(rn_add(rn_mul(p.x, p.x), rn_mul(p.y, p.y)),
                              rn_mul(p.z, p.z));
            float dot = __builtin_fmaf(az, p.z,
                         __builtin_fmaf(ay, p.y, rn_mul(ax, p.x)));
            float dd = __builtin_fmaf(-2.0f, dot, rn_add(a2, b2));
            ins_lex(dd, __float_as_int(p.w), d1, i1, d2, i2);
            p = pn;
        }
        float b2 = rn_add(rn_add(rn_mul(p.x, p.x), rn_mul(p.y, p.y)),
                          rn_mul(p.z, p.z));
        float dot = __builtin_fmaf(az, p.z,
                     __builtin_fmaf(ay, p.y, rn_mul(ax, p.x)));
        float dd = __builtin_fmaf(-2.0f, dot, rn_add(a2, b2));
        ins_lex(dd, __float_as_int(p.w), d1, i1, d2, i2);
    };

    // analytic density-adaptive initial radius (no memory probe):
    // local density ~ exp(-r^2/2) => 2NN distance scale ~ exp(+r^2/6)
    float R = fminf(0.13f * __expf(a2 * (1.0f / 6.0f)), 2.5f);

    int pxlo = 0, pxhi = -1, pylo = 0, pyhi = -1, pzlo = 0, pzhi = -1; // empty
#pragma unroll 1
    for (int round = 0; round < 12; ++round) {
        int xlo = cellco(ax - R), xhi = cellco(ax + R);
        int ylo = cellco(ay - R), yhi = cellco(ay + R);
        int zlo = cellco(az - R), zhi = cellco(az + R);
        int sy = yhi - ylo + 1, sz = zhi - zlo + 1;
        int rows = sy * sz;
        int SUB = 64 / rows; if (SUB < 1) SUB = 1;   // lanes per row
        int slots = rows * SUB;
        for (int k = lane; k < slots; k += 64) {
            int row = k / SUB, sub = k - row * SUB;
            int dz = row / sy, dy = row - dz * sy;
            int zz = zlo + dz, yy = ylo + dy;
            int rowbase = (zz * GS + yy) * GS;
            bool inPrev = (zz >= pzlo && zz <= pzhi && yy >= pylo && yy <= pyhi);
            if (inPrev) {
                // only the two x-subranges outside the previous box are new
                scan_range(st[rowbase + xlo], st[rowbase + pxlo], sub, SUB);
                scan_range(st[rowbase + pxhi + 1], st[rowbase + xhi + 1], sub, SUB);
            } else {
                scan_range(st[rowbase + xlo], st[rowbase + xhi + 1], sub, SUB);
            }
        }
        pxlo = xlo; pxhi = xhi; pylo = ylo; pyhi = yhi; pzlo = zlo; pzhi = zhi;

        // stop bound from the scanned-box faces (>= R on non-edge axes)
        float bnd = INF_F;
        if (xlo > 0)      bnd = fminf(bnd, ax - (LOC + xlo * CWID));
        if (xhi < GS - 1) bnd = fminf(bnd, (LOC + (xhi + 1) * CWID) - ax);
        if (ylo > 0)      bnd = fminf(bnd, ay - (LOC + ylo * CWID));
        if (yhi < GS - 1) bnd = fminf(bnd, (LOC + (yhi + 1) * CWID) - ay);
        if (zlo > 0)      bnd = fminf(bnd, az - (LOC + zlo * CWID));
        if (zhi < GS - 1) bnd = fminf(bnd, (LOC + (zhi + 1) * CWID) - az);
        if (bnd == INF_F) break;                 // whole grid scanned

        // cheap exact 2nd-smallest VALUE across lanes for the stop test
        float p1 = d1, p2 = d2;
#pragma unroll
        for (int mk = 1; mk < 64; mk <<= 1) {
            float o1 = __shfl_xor(p1, mk);
            float o2 = __shfl_xor(p2, mk);
            vpair_merge(p1, p2, o1, o2);
        }
        if (p2 < bnd * bnd - MARG) break;        // rigorous exact stop
        R *= 2.0f;
    }

    // ---- one exact lex butterfly (privates pure; disjoint point sets) ----
    float t1 = d1, t2 = d2; int u1 = i1, u2 = i2;
#pragma unroll
    for (int mk = 1; mk < 64; mk <<= 1) {
        float o1 = __shfl_xor(t1, mk); int p1 = __shfl_xor(u1, mk);
        float o2 = __shfl_xor(t2, mk); int p2 = __shfl_xor(u2, mk);
        ins_lex(o1, p1, t1, u1, t2, u2);
        ins_lex2(o2, p2, t2, u2);
    }

    // fused gather: result uniform across the wave; 64 lanes x float4 = row
    const float* feats = side ? tgt : src;
    const float4* sp = (const float4*)(feats + (size_t)u2 * C_F);
    float4* dp = (float4*)(out + (size_t)qid * C_F);
    dp[lane] = sp[lane];
}

extern "C" void kernel_launch(void* const* d_in, const int* in_sizes, int n_in,
                              void* d_out, int out_size, void* d_ws, size_t ws_size,
                              hipStream_t stream) {
    const float* src  = (const float*)d_in[0];
    const float* tgt  = (const float*)d_in[1];
    const float* c0   = (const float*)d_in[2];  // src_coords   (N,3)
    const float* c1   = (const float*)d_in[3];  // tgt_coords   (N,3)
    const float* sh0  = (const float*)d_in[4];  // src_shortcut (M,3)
    const float* sh1  = (const float*)d_in[5];  // tgt_shortcut (M,3)
    float* out = (float*)d_out;

    char* w = (char*)d_ws;
    float4* pts4   = (float4*)(w);                       // 1,048,576
    int*    cid    = (int*)(w + 1048576);                //   262,144
    int*    counts = (int*)(w + 1310720);                //   262,144
    int*    starts = (int*)(w + 1572864);                //   262,148 (65537)
    int*    bsum   = (int*)(w + 1835012);                //     1,024

    hipMemsetAsync(counts, 0, (size_t)TOTP * sizeof(int), stream);

    hipLaunchKernelGGL(build_cells, dim3(TOTP / 256), dim3(256), 0, stream,
                       c0, c1, counts, cid);
    hipLaunchKernelGGL(scan1, dim3(TOTP / 256), dim3(256), 0, stream,
                       counts, starts, bsum);
    hipLaunchKernelGGL(scan23, dim3(TOTP / 256), dim3(256), 0, stream,
                       starts, bsum);
    hipLaunchKernelGGL(scatter, dim3(TOTP / 256), dim3(256), 0, stream,
                       c0, c1, cid, starts, counts, pts4);
    hipLaunchKernelGGL(query2nn, dim3(TOTQ / 2), dim3(128), 0, stream,
                       src, tgt, sh0, sh1, pts4, starts, out);
}

// Round 22
// 88.638 us; speedup vs baseline: 1.1588x; 1.1588x over previous
//
#include <hip/hip_runtime.h>

#define N_PTS 32768
#define M_Q   8192
#define C_F   256
#define GS    32
#define NC    (GS * GS * GS)          // 32768 cells per side
#define TOTP  (2 * N_PTS)             // 65536 points
#define TOTQ  (2 * M_Q)               // 16384 queries
#define LOC   (-4.4f)
#define CWID  (8.8f / GS)             // 0.275
#define INVW  (GS / 8.8f)
#define MARG  2e-4f
#define INF_F __int_as_float(0x7f800000)
#define MAXI  0x7fffffff

__device__ __forceinline__ float rn_mul(float a, float b) { return __fmul_rn(a, b); }
__device__ __forceinline__ float rn_add(float a, float b) { return __fadd_rn(a, b); }

__device__ __forceinline__ int cellco(float v) {
    int c = (int)floorf((v - LOC) * INVW);
    return c < 0 ? 0 : (c > GS - 1 ? GS - 1 : c);
}

// exact lexicographic (d,i) insert into running top-2 pair
__device__ __forceinline__ void ins_lex(float d, int i, float& b1, int& j1,
                                        float& b2, int& j2) {
    bool lt1 = (d < b1) || (d == b1 && i < j1);
    bool lt2 = (d < b2) || (d == b2 && i < j2);
    b2 = lt1 ? b1 : (lt2 ? d : b2);
    j2 = lt1 ? j1 : (lt2 ? i : j2);
    b1 = lt1 ? d : b1;
    j1 = lt1 ? i : j1;
}
__device__ __forceinline__ void ins_lex2(float d, int i, float& b2, int& j2) {
    bool lt2 = (d < b2) || (d == b2 && i < j2);
    b2 = lt2 ? d : b2;
    j2 = lt2 ? i : j2;
}

// merge two sorted value-pairs -> two smallest values (multiset-exact)
__device__ __forceinline__ void vpair_merge(float& a1, float& a2, float b1, float b2) {
    float n1 = fminf(a1, b1);
    float n2 = fminf(fmaxf(a1, b1), fminf(a2, b2));
    a1 = n1; a2 = n2;
}

// K1: per-point cell id + histogram
__global__ __launch_bounds__(256) void build_cells(
    const float* __restrict__ c0, const float* __restrict__ c1,
    int* __restrict__ counts, int* __restrict__ cid)
{
    int t = blockIdx.x * 256 + threadIdx.x;     // 0..65535
    int side = t >> 15, n = t & (N_PTS - 1);
    const float* c = side ? c1 : c0;
    float x = c[n * 3], y = c[n * 3 + 1], z = c[n * 3 + 2];
    int g = side * NC + (cellco(z) * GS + cellco(y)) * GS + cellco(x);
    cid[t] = g;
    atomicAdd(&counts[g], 1);
}

// K2: per-256-block exclusive scan, emit block sums
__global__ __launch_bounds__(256) void scan1(const int* __restrict__ counts,
                                             int* __restrict__ starts,
                                             int* __restrict__ bsum)
{
    __shared__ int s[256];
    int b = blockIdx.x, tid = threadIdx.x;
    int v = counts[b * 256 + tid];
    s[tid] = v;
    __syncthreads();
    for (int o = 1; o < 256; o <<= 1) {
        int u = (tid >= o) ? s[tid - o] : 0;
        __syncthreads();
        s[tid] += u;
        __syncthreads();
    }
    starts[b * 256 + tid] = s[tid] - v;   // exclusive
    if (tid == 255) bsum[b] = s[255];
}

// K3: fused scan2+scan3 — each block locally scans the 256 block sums,
// takes its own exclusive prefix, adds to its starts slice.
__global__ __launch_bounds__(256) void scan23(int* __restrict__ starts,
                                              const int* __restrict__ bsum)
{
    __shared__ int s[256];
    int b = blockIdx.x, tid = threadIdx.x;
    int v = bsum[tid];
    s[tid] = v;
    __syncthreads();
    for (int o = 1; o < 256; o <<= 1) {
        int u = (tid >= o) ? s[tid - o] : 0;
        __syncthreads();
        s[tid] += u;
        __syncthreads();
    }
    int off = s[b] - bsum[b];             // exclusive prefix of bsum at b
    starts[b * 256 + tid] += off;
    if (b == 0 && tid == 0) starts[TOTP] = TOTP;   // sentinel
}

// K5: scatter points into cell-sorted pool; index packed into .w (raw bits)
__global__ __launch_bounds__(256) void scatter(
    const float* __restrict__ c0, const float* __restrict__ c1,
    const int* __restrict__ cid, const int* __restrict__ starts,
    int* __restrict__ counts, float4* __restrict__ pts4)
{
    int t = blockIdx.x * 256 + threadIdx.x;
    int side = t >> 15, n = t & (N_PTS - 1);
    const float* c = side ? c1 : c0;
    float x = c[n * 3], y = c[n * 3 + 1], z = c[n * 3 + 2];
    int g = cid[t];
    int pos = starts[g] + (atomicSub(&counts[g], 1) - 1);
    pts4[pos] = make_float4(x, y, z, __int_as_float(n));
}

// K6: one WAVE per query; 2 independent waves per 128-thread block.
// Query-centered boxes, ROW-parallel scanning (rows x-contiguous -> one
// starts-pair per row). Analytic density-adaptive R0 = 0.095*exp(a2/6):
// calibrated so R ~ 1.55x expected 2NN distance at the local Gaussian
// density (lambda ~ exp(-a2/2) => d2 ~ exp(+a2/6); d2(0) ~ 0.061).
// Point index rides in pts4.w; b2 recomputed with the exact numpy chain
// (bit-identical dd). Nested boxes + row x-subrange skip => exactly-once.
// Value-only stop per round; one exact lex butterfly at the end.
__global__ __launch_bounds__(128) void query2nn(
    const float* __restrict__ src, const float* __restrict__ tgt,
    const float* __restrict__ sc0, const float* __restrict__ sc1,
    const float4* __restrict__ pts4, const int* __restrict__ starts,
    float* __restrict__ out)
{
    int lane = threadIdx.x & 63;
    int wv   = threadIdx.x >> 6;
    int qid  = blockIdx.x * 2 + wv;          // 0..16383
    int side = qid >> 13, q = qid & (M_Q - 1);
    const float* sc = side ? sc1 : sc0;

    float ax = sc[q * 3], ay = sc[q * 3 + 1], az = sc[q * 3 + 2];
    float a2 = rn_add(rn_add(rn_mul(ax, ax), rn_mul(ay, ay)), rn_mul(az, az));
    const int* st = starts + side * NC;

    float d1 = INF_F, d2 = INF_F;            // per-lane privates (disjoint pts)
    int   i1 = MAXI,  i2 = MAXI;

    // scan points [s0+sub, s1) stride `step`, 2-deep prefetch; ONE load stream
    auto scan_range = [&](int s0, int s1, int sub, int step) {
        int j = s0 + sub;
        if (j >= s1) return;
        float4 p = pts4[j];
        for (j += step; j < s1; j += step) {
            float4 pn = pts4[j];
            float b2 = rn_add(rn_add(rn_mul(p.x, p.x), rn_mul(p.y, p.y)),
                              rn_mul(p.z, p.z));
            float dot = __builtin_fmaf(az, p.z,
                         __builtin_fmaf(ay, p.y, rn_mul(ax, p.x)));
            float dd = __builtin_fmaf(-2.0f, dot, rn_add(a2, b2));
            ins_lex(dd, __float_as_int(p.w), d1, i1, d2, i2);
            p = pn;
        }
        float b2 = rn_add(rn_add(rn_mul(p.x, p.x), rn_mul(p.y, p.y)),
                          rn_mul(p.z, p.z));
        float dot = __builtin_fmaf(az, p.z,
                     __builtin_fmaf(ay, p.y, rn_mul(ax, p.x)));
        float dd = __builtin_fmaf(-2.0f, dot, rn_add(a2, b2));
        ins_lex(dd, __float_as_int(p.w), d1, i1, d2, i2);
    };

    // analytic density-adaptive initial radius (no memory probe), calibrated:
    // R = 1.55 * d2_expected(a2) = 0.095 * exp(a2/6)
    float R = fminf(0.095f * __expf(a2 * (1.0f / 6.0f)), 3.0f);

    int pxlo = 0, pxhi = -1, pylo = 0, pyhi = -1, pzlo = 0, pzhi = -1; // empty
#pragma unroll 1
    for (int round = 0; round < 12; ++round) {
        int xlo = cellco(ax - R), xhi = cellco(ax + R);
        int ylo = cellco(ay - R), yhi = cellco(ay + R);
        int zlo = cellco(az - R), zhi = cellco(az + R);
        int sy = yhi - ylo + 1, sz = zhi - zlo + 1;
        int rows = sy * sz;
        int SUB = 64 / rows; if (SUB < 1) SUB = 1;   // lanes per row
        int slots = rows * SUB;
        for (int k = lane; k < slots; k += 64) {
            int row = k / SUB, sub = k - row * SUB;
            int dz = row / sy, dy = row - dz * sy;
            int zz = zlo + dz, yy = ylo + dy;
            int rowbase = (zz * GS + yy) * GS;
            bool inPrev = (zz >= pzlo && zz <= pzhi && yy >= pylo && yy <= pyhi);
            if (inPrev) {
                // only the two x-subranges outside the previous box are new
                scan_range(st[rowbase + xlo], st[rowbase + pxlo], sub, SUB);
                scan_range(st[rowbase + pxhi + 1], st[rowbase + xhi + 1], sub, SUB);
            } else {
                scan_range(st[rowbase + xlo], st[rowbase + xhi + 1], sub, SUB);
            }
        }
        pxlo = xlo; pxhi = xhi; pylo = ylo; pyhi = yhi; pzlo = zlo; pzhi = zhi;

        // stop bound from the scanned-box faces (>= R on non-edge axes)
        float bnd = INF_F;
        if (xlo > 0)      bnd = fminf(bnd, ax - (LOC + xlo * CWID));
        if (xhi < GS - 1) bnd = fminf(bnd, (LOC + (xhi + 1) * CWID) - ax);
        if (ylo > 0)      bnd = fminf(bnd, ay - (LOC + ylo * CWID));
        if (yhi < GS - 1) bnd = fminf(bnd, (LOC + (yhi + 1) * CWID) - ay);
        if (zlo > 0)      bnd = fminf(bnd, az - (LOC + zlo * CWID));
        if (zhi < GS - 1) bnd = fminf(bnd, (LOC + (zhi + 1) * CWID) - az);
        if (bnd == INF_F) break;                 // whole grid scanned

        // cheap exact 2nd-smallest VALUE across lanes for the stop test
        float p1 = d1, p2 = d2;
#pragma unroll
        for (int mk = 1; mk < 64; mk <<= 1) {
            float o1 = __shfl_xor(p1, mk);
            float o2 = __shfl_xor(p2, mk);
            vpair_merge(p1, p2, o1, o2);
        }
        if (p2 < bnd * bnd - MARG) break;        // rigorous exact stop
        R *= 2.0f;
    }

    // ---- one exact lex butterfly (privates pure; disjoint point sets) ----
    float t1 = d1, t2 = d2; int u1 = i1, u2 = i2;
#pragma unroll
    for (int mk = 1; mk < 64; mk <<= 1) {
        float o1 = __shfl_xor(t1, mk); int p1 = __shfl_xor(u1, mk);
        float o2 = __shfl_xor(t2, mk); int p2 = __shfl_xor(u2, mk);
        ins_lex(o1, p1, t1, u1, t2, u2);
        ins_lex2(o2, p2, t2, u2);
    }

    // fused gather: result uniform across the wave; 64 lanes x float4 = row
    const float* feats = side ? tgt : src;
    const float4* sp = (const float4*)(feats + (size_t)u2 * C_F);
    float4* dp = (float4*)(out + (size_t)qid * C_F);
    dp[lane] = sp[lane];
}

extern "C" void kernel_launch(void* const* d_in, const int* in_sizes, int n_in,
                              void* d_out, int out_size, void* d_ws, size_t ws_size,
                              hipStream_t stream) {
    const float* src  = (const float*)d_in[0];
    const float* tgt  = (const float*)d_in[1];
    const float* c0   = (const float*)d_in[2];  // src_coords   (N,3)
    const float* c1   = (const float*)d_in[3];  // tgt_coords   (N,3)
    const float* sh0  = (const float*)d_in[4];  // src_shortcut (M,3)
    const float* sh1  = (const float*)d_in[5];  // tgt_shortcut (M,3)
    float* out = (float*)d_out;

    char* w = (char*)d_ws;
    float4* pts4   = (float4*)(w);                       // 1,048,576
    int*    cid    = (int*)(w + 1048576);                //   262,144
    int*    counts = (int*)(w + 1310720);                //   262,144
    int*    starts = (int*)(w + 1572864);                //   262,148 (65537)
    int*    bsum   = (int*)(w + 1835012);                //     1,024

    hipMemsetAsync(counts, 0, (size_t)TOTP * sizeof(int), stream);

    hipLaunchKernelGGL(build_cells, dim3(TOTP / 256), dim3(256), 0, stream,
                       c0, c1, counts, cid);
    hipLaunchKernelGGL(scan1, dim3(TOTP / 256), dim3(256), 0, stream,
                       counts, starts, bsum);
    hipLaunchKernelGGL(scan23, dim3(TOTP / 256), dim3(256), 0, stream,
                       starts, bsum);
    hipLaunchKernelGGL(scatter, dim3(TOTP / 256), dim3(256), 0, stream,
                       c0, c1, cid, starts, counts, pts4);
    hipLaunchKernelGGL(query2nn, dim3(TOTQ / 2), dim3(128), 0, stream,
                       src, tgt, sh0, sh1, pts4, starts, out);
}

// Round 23
// 53.369 us; speedup vs baseline: 1.9246x; 1.6608x over previous
//
#include <hip/hip_runtime.h>

#define N_PTS 32768
#define M_Q   8192
#define C_F   256
#define GS    32
#define NC    (GS * GS * GS)          // 32768 cells per side
#define TOTP  (2 * N_PTS)             // 65536 points
#define TOTQ  (2 * M_Q)               // 16384 queries
#define LOC   (-4.4f)
#define CWID  (8.8f / GS)             // 0.275
#define INVW  (GS / 8.8f)
#define MARG  2e-4f
#define INF_F __int_as_float(0x7f800000)
#define MAXI  0x7fffffff

__device__ __forceinline__ float rn_mul(float a, float b) { return __fmul_rn(a, b); }
__device__ __forceinline__ float rn_add(float a, float b) { return __fadd_rn(a, b); }

__device__ __forceinline__ int cellco(float v) {
    int c = (int)floorf((v - LOC) * INVW);
    return c < 0 ? 0 : (c > GS - 1 ? GS - 1 : c);
}

// exact lexicographic (d,i) insert into running top-2 pair
__device__ __forceinline__ void ins_lex(float d, int i, float& b1, int& j1,
                                        float& b2, int& j2) {
    bool lt1 = (d < b1) || (d == b1 && i < j1);
    bool lt2 = (d < b2) || (d == b2 && i < j2);
    b2 = lt1 ? b1 : (lt2 ? d : b2);
    j2 = lt1 ? j1 : (lt2 ? i : j2);
    b1 = lt1 ? d : b1;
    j1 = lt1 ? i : j1;
}
__device__ __forceinline__ void ins_lex2(float d, int i, float& b2, int& j2) {
    bool lt2 = (d < b2) || (d == b2 && i < j2);
    b2 = lt2 ? d : b2;
    j2 = lt2 ? i : j2;
}

// merge two sorted value-pairs -> two smallest values (multiset-exact)
__device__ __forceinline__ void vpair_merge(float& a1, float& a2, float b1, float b2) {
    float n1 = fminf(a1, b1);
    float n2 = fminf(fmaxf(a1, b1), fminf(a2, b2));
    a1 = n1; a2 = n2;
}

// K1: per-point cell id + histogram
__global__ __launch_bounds__(256) void build_cells(
    const float* __restrict__ c0, const float* __restrict__ c1,
    int* __restrict__ counts, int* __restrict__ cid)
{
    int t = blockIdx.x * 256 + threadIdx.x;     // 0..65535
    int side = t >> 15, n = t & (N_PTS - 1);
    const float* c = side ? c1 : c0;
    float x = c[n * 3], y = c[n * 3 + 1], z = c[n * 3 + 2];
    int g = side * NC + (cellco(z) * GS + cellco(y)) * GS + cellco(x);
    cid[t] = g;
    atomicAdd(&counts[g], 1);
}

// K2: per-256-block exclusive scan, emit block sums
__global__ __launch_bounds__(256) void scan1(const int* __restrict__ counts,
                                             int* __restrict__ starts,
                                             int* __restrict__ bsum)
{
    __shared__ int s[256];
    int b = blockIdx.x, tid = threadIdx.x;
    int v = counts[b * 256 + tid];
    s[tid] = v;
    __syncthreads();
    for (int o = 1; o < 256; o <<= 1) {
        int u = (tid >= o) ? s[tid - o] : 0;
        __syncthreads();
        s[tid] += u;
        __syncthreads();
    }
    starts[b * 256 + tid] = s[tid] - v;   // exclusive
    if (tid == 255) bsum[b] = s[255];
}

// K3: fused scan2+scan3 — each block locally scans the 256 block sums,
// takes its own exclusive prefix, adds to its starts slice.
__global__ __launch_bounds__(256) void scan23(int* __restrict__ starts,
                                              const int* __restrict__ bsum)
{
    __shared__ int s[256];
    int b = blockIdx.x, tid = threadIdx.x;
    int v = bsum[tid];
    s[tid] = v;
    __syncthreads();
    for (int o = 1; o < 256; o <<= 1) {
        int u = (tid >= o) ? s[tid - o] : 0;
        __syncthreads();
        s[tid] += u;
        __syncthreads();
    }
    int off = s[b] - bsum[b];             // exclusive prefix of bsum at b
    starts[b * 256 + tid] += off;
    if (b == 0 && tid == 0) starts[TOTP] = TOTP;   // sentinel
}

// K5: scatter points into cell-sorted pool; index packed into .w (raw bits)
__global__ __launch_bounds__(256) void scatter(
    const float* __restrict__ c0, const float* __restrict__ c1,
    const int* __restrict__ cid, const int* __restrict__ starts,
    int* __restrict__ counts, float4* __restrict__ pts4)
{
    int t = blockIdx.x * 256 + threadIdx.x;
    int side = t >> 15, n = t & (N_PTS - 1);
    const float* c = side ? c1 : c0;
    float x = c[n * 3], y = c[n * 3 + 1], z = c[n * 3 + 2];
    int g = cid[t];
    int pos = starts[g] + (atomicSub(&counts[g], 1) - 1);
    pts4[pos] = make_float4(x, y, z, __int_as_float(n));
}

// K6: one WAVE per query; 2 independent waves per 128-thread block.
// Query-centered boxes, ROW-parallel scanning (rows x-contiguous -> one
// starts-pair per row). R0 from the MEASURED n0-probe ladder (r20: best).
// Point index rides in pts4.w; b2 recomputed with the exact numpy chain
// (bit-identical dd). Nested boxes + row x-subrange skip => exactly-once.
// Value-only stop per round; one exact lex butterfly at the end.
__global__ __launch_bounds__(128) void query2nn(
    const float* __restrict__ src, const float* __restrict__ tgt,
    const float* __restrict__ sc0, const float* __restrict__ sc1,
    const float4* __restrict__ pts4, const int* __restrict__ starts,
    float* __restrict__ out)
{
    int lane = threadIdx.x & 63;
    int wv   = threadIdx.x >> 6;
    int qid  = blockIdx.x * 2 + wv;          // 0..16383
    int side = qid >> 13, q = qid & (M_Q - 1);
    const float* sc = side ? sc1 : sc0;

    float ax = sc[q * 3], ay = sc[q * 3 + 1], az = sc[q * 3 + 2];
    float a2 = rn_add(rn_add(rn_mul(ax, ax), rn_mul(ay, ay)), rn_mul(az, az));
    const int* st = starts + side * NC;

    float d1 = INF_F, d2 = INF_F;            // per-lane privates (disjoint pts)
    int   i1 = MAXI,  i2 = MAXI;

    // scan points [s0+sub, s1) stride `step`, 2-deep prefetch; ONE load stream
    auto scan_range = [&](int s0, int s1, int sub, int step) {
        int j = s0 + sub;
        if (j >= s1) return;
        float4 p = pts4[j];
        for (j += step; j < s1; j += step) {
            float4 pn = pts4[j];
            float b2 = rn_add(rn_add(rn_mul(p.x, p.x), rn_mul(p.y, p.y)),
                              rn_mul(p.z, p.z));
            float dot = __builtin_fmaf(az, p.z,
                         __builtin_fmaf(ay, p.y, rn_mul(ax, p.x)));
            float dd = __builtin_fmaf(-2.0f, dot, rn_add(a2, b2));
            ins_lex(dd, __float_as_int(p.w), d1, i1, d2, i2);
            p = pn;
        }
        float b2 = rn_add(rn_add(rn_mul(p.x, p.x), rn_mul(p.y, p.y)),
                          rn_mul(p.z, p.z));
        float dot = __builtin_fmaf(az, p.z,
                     __builtin_fmaf(ay, p.y, rn_mul(ax, p.x)));
        float dd = __builtin_fmaf(-2.0f, dot, rn_add(a2, b2));
        ins_lex(dd, __float_as_int(p.w), d1, i1, d2, i2);
    };

    // measured density-adaptive initial radius from the query cell's count
    int cx = cellco(ax), cy = cellco(ay), cz = cellco(az);
    int cc = (cz * GS + cy) * GS + cx;
    int n0 = st[cc + 1] - st[cc];            // wave-uniform probe (r20: best)
    float R = (n0 >= 6) ? 0.12f : ((n0 >= 2) ? 0.19f : 0.30f);

    int pxlo = 0, pxhi = -1, pylo = 0, pyhi = -1, pzlo = 0, pzhi = -1; // empty
#pragma unroll 1
    for (int round = 0; round < 12; ++round) {
        int xlo = cellco(ax - R), xhi = cellco(ax + R);
        int ylo = cellco(ay - R), yhi = cellco(ay + R);
        int zlo = cellco(az - R), zhi = cellco(az + R);
        int sy = yhi - ylo + 1, sz = zhi - zlo + 1;
        int rows = sy * sz;
        int SUB = 64 / rows; if (SUB < 1) SUB = 1;   // lanes per row
        int slots = rows * SUB;
        for (int k = lane; k < slots; k += 64) {
            int row = k / SUB, sub = k - row * SUB;
            int dz = row / sy, dy = row - dz * sy;
            int zz = zlo + dz, yy = ylo + dy;
            int rowbase = (zz * GS + yy) * GS;
            bool inPrev = (zz >= pzlo && zz <= pzhi && yy >= pylo && yy <= pyhi);
            if (inPrev) {
                // only the two x-subranges outside the previous box are new
                scan_range(st[rowbase + xlo], st[rowbase + pxlo], sub, SUB);
                scan_range(st[rowbase + pxhi + 1], st[rowbase + xhi + 1], sub, SUB);
            } else {
                scan_range(st[rowbase + xlo], st[rowbase + xhi + 1], sub, SUB);
            }
        }
        pxlo = xlo; pxhi = xhi; pylo = ylo; pyhi = yhi; pzlo = zlo; pzhi = zhi;

        // stop bound from the scanned-box faces (>= R on non-edge axes)
        float bnd = INF_F;
        if (xlo > 0)      bnd = fminf(bnd, ax - (LOC + xlo * CWID));
        if (xhi < GS - 1) bnd = fminf(bnd, (LOC + (xhi + 1) * CWID) - ax);
        if (ylo > 0)      bnd = fminf(bnd, ay - (LOC + ylo * CWID));
        if (yhi < GS - 1) bnd = fminf(bnd, (LOC + (yhi + 1) * CWID) - ay);
        if (zlo > 0)      bnd = fminf(bnd, az - (LOC + zlo * CWID));
        if (zhi < GS - 1) bnd = fminf(bnd, (LOC + (zhi + 1) * CWID) - az);
        if (bnd == INF_F) break;                 // whole grid scanned

        // cheap exact 2nd-smallest VALUE across lanes for the stop test
        float p1 = d1, p2 = d2;
#pragma unroll
        for (int mk = 1; mk < 64; mk <<= 1) {
            float o1 = __shfl_xor(p1, mk);
            float o2 = __shfl_xor(p2, mk);
            vpair_merge(p1, p2, o1, o2);
        }
        if (p2 < bnd * bnd - MARG) break;        // rigorous exact stop
        R *= 2.0f;
    }

    // ---- one exact lex butterfly (privates pure; disjoint point sets) ----
    float t1 = d1, t2 = d2; int u1 = i1, u2 = i2;
#pragma unroll
    for (int mk = 1; mk < 64; mk <<= 1) {
        float o1 = __shfl_xor(t1, mk); int p1 = __shfl_xor(u1, mk);
        float o2 = __shfl_xor(t2, mk); int p2 = __shfl_xor(u2, mk);
        ins_lex(o1, p1, t1, u1, t2, u2);
        ins_lex2(o2, p2, t2, u2);
    }

    // fused gather: result uniform across the wave; 64 lanes x float4 = row
    const float* feats = side ? tgt : src;
    const float4* sp = (const float4*)(feats + (size_t)u2 * C_F);
    float4* dp = (float4*)(out + (size_t)qid * C_F);
    dp[lane] = sp[lane];
}

extern "C" void kernel_launch(void* const* d_in, const int* in_sizes, int n_in,
                              void* d_out, int out_size, void* d_ws, size_t ws_size,
                              hipStream_t stream) {
    const float* src  = (const float*)d_in[0];
    const float* tgt  = (const float*)d_in[1];
    const float* c0   = (const float*)d_in[2];  // src_coords   (N,3)
    const float* c1   = (const float*)d_in[3];  // tgt_coords   (N,3)
    const float* sh0  = (const float*)d_in[4];  // src_shortcut (M,3)
    const float* sh1  = (const float*)d_in[5];  // tgt_shortcut (M,3)
    float* out = (float*)d_out;

    char* w = (char*)d_ws;
    float4* pts4   = (float4*)(w);                       // 1,048,576
    int*    cid    = (int*)(w + 1048576);                //   262,144
    int*    counts = (int*)(w + 1310720);                //   262,144
    int*    starts = (int*)(w + 1572864);                //   262,148 (65537)
    int*    bsum   = (int*)(w + 1835012);                //     1,024

    hipMemsetAsync(counts, 0, (size_t)TOTP * sizeof(int), stream);

    hipLaunchKernelGGL(build_cells, dim3(TOTP / 256), dim3(256), 0, stream,
                       c0, c1, counts, cid);
    hipLaunchKernelGGL(scan1, dim3(TOTP / 256), dim3(256), 0, stream,
                       counts, starts, bsum);
    hipLaunchKernelGGL(scan23, dim3(TOTP / 256), dim3(256), 0, stream,
                       starts, bsum);
    hipLaunchKernelGGL(scatter, dim3(TOTP / 256), dim3(256), 0, stream,
                       c0, c1, cid, starts, counts, pts4);
    hipLaunchKernelGGL(query2nn, dim3(TOTQ / 2), dim3(128), 0, stream,
                       src, tgt, sh0, sh1, pts4, starts, out);
}

// Round 24
// 47.108 us; speedup vs baseline: 2.1804x; 1.1329x over previous
//
#include <hip/hip_runtime.h>

#define N_PTS 32768
#define M_Q   8192
#define C_F   256
#define GS    32
#define NC    (GS * GS * GS)          // 32768 cells per side
#define TOTP  (2 * N_PTS)             // 65536 points
#define TOTQ  (2 * M_Q)               // 16384 queries
#define LOC   (-4.4f)
#define CWID  (8.8f / GS)             // 0.275
#define INVW  (GS / 8.8f)
#define MARG  2e-4f
#define INF_F __int_as_float(0x7f800000)
#define MAXI  0x7fffffff

__device__ __forceinline__ float rn_mul(float a, float b) { return __fmul_rn(a, b); }
__device__ __forceinline__ float rn_add(float a, float b) { return __fadd_rn(a, b); }

__device__ __forceinline__ int cellco(float v) {
    int c = (int)floorf((v - LOC) * INVW);
    return c < 0 ? 0 : (c > GS - 1 ? GS - 1 : c);
}

// exact lexicographic (d,i) insert into running top-2 pair
__device__ __forceinline__ void ins_lex(float d, int i, float& b1, int& j1,
                                        float& b2, int& j2) {
    bool lt1 = (d < b1) || (d == b1 && i < j1);
    bool lt2 = (d < b2) || (d == b2 && i < j2);
    b2 = lt1 ? b1 : (lt2 ? d : b2);
    j2 = lt1 ? j1 : (lt2 ? i : j2);
    b1 = lt1 ? d : b1;
    j1 = lt1 ? i : j1;
}
__device__ __forceinline__ void ins_lex2(float d, int i, float& b2, int& j2) {
    bool lt2 = (d < b2) || (d == b2 && i < j2);
    b2 = lt2 ? d : b2;
    j2 = lt2 ? i : j2;
}

// merge two sorted value-pairs -> two smallest values (multiset-exact)
__device__ __forceinline__ void vpair_merge(float& a1, float& a2, float b1, float b2) {
    float n1 = fminf(a1, b1);
    float n2 = fminf(fmaxf(a1, b1), fminf(a2, b2));
    a1 = n1; a2 = n2;
}

// K1: per-point cell id + histogram
__global__ __launch_bounds__(256) void build_cells(
    const float* __restrict__ c0, const float* __restrict__ c1,
    int* __restrict__ counts, int* __restrict__ cid)
{
    int t = blockIdx.x * 256 + threadIdx.x;     // 0..65535
    int side = t >> 15, n = t & (N_PTS - 1);
    const float* c = side ? c1 : c0;
    float x = c[n * 3], y = c[n * 3 + 1], z = c[n * 3 + 2];
    int g = side * NC + (cellco(z) * GS + cellco(y)) * GS + cellco(x);
    cid[t] = g;
    atomicAdd(&counts[g], 1);
}

// K2: per-256-block exclusive scan, emit block sums
__global__ __launch_bounds__(256) void scan1(const int* __restrict__ counts,
                                             int* __restrict__ starts,
                                             int* __restrict__ bsum)
{
    __shared__ int s[256];
    int b = blockIdx.x, tid = threadIdx.x;
    int v = counts[b * 256 + tid];
    s[tid] = v;
    __syncthreads();
    for (int o = 1; o < 256; o <<= 1) {
        int u = (tid >= o) ? s[tid - o] : 0;
        __syncthreads();
        s[tid] += u;
        __syncthreads();
    }
    starts[b * 256 + tid] = s[tid] - v;   // exclusive
    if (tid == 255) bsum[b] = s[255];
}

// K3: fused scan2+scan3 — each block locally scans the 256 block sums,
// takes its own exclusive prefix, adds to its starts slice.
__global__ __launch_bounds__(256) void scan23(int* __restrict__ starts,
                                              const int* __restrict__ bsum)
{
    __shared__ int s[256];
    int b = blockIdx.x, tid = threadIdx.x;
    int v = bsum[tid];
    s[tid] = v;
    __syncthreads();
    for (int o = 1; o < 256; o <<= 1) {
        int u = (tid >= o) ? s[tid - o] : 0;
        __syncthreads();
        s[tid] += u;
        __syncthreads();
    }
    int off = s[b] - bsum[b];             // exclusive prefix of bsum at b
    starts[b * 256 + tid] += off;
    if (b == 0 && tid == 0) starts[TOTP] = TOTP;   // sentinel
}

// K5: scatter points into cell-sorted pool; index packed into .w (raw bits)
__global__ __launch_bounds__(256) void scatter(
    const float* __restrict__ c0, const float* __restrict__ c1,
    const int* __restrict__ cid, const int* __restrict__ starts,
    int* __restrict__ counts, float4* __restrict__ pts4)
{
    int t = blockIdx.x * 256 + threadIdx.x;
    int side = t >> 15, n = t & (N_PTS - 1);
    const float* c = side ? c1 : c0;
    float x = c[n * 3], y = c[n * 3 + 1], z = c[n * 3 + 2];
    int g = cid[t];
    int pos = starts[g] + (atomicSub(&counts[g], 1) - 1);
    pts4[pos] = make_float4(x, y, z, __int_as_float(n));
}

// K6: one WAVE per query; 2 independent waves per 128-thread block.
// Query-centered boxes, ROW-parallel scanning. R0 from the measured n0-probe
// ladder. NEW: certified-radius jump — if the stop fails with finite p2, the
// next box radius is sqrt(p2+MARG) (the exact radius needed to certify), so
// any query needs at most ONE round after its first content round. Empty
// rounds still double. Correctness rests only on the unchanged break
// conditions (value-exact stop with MARG, or full-grid coverage).
__global__ __launch_bounds__(128) void query2nn(
    const float* __restrict__ src, const float* __restrict__ tgt,
    const float* __restrict__ sc0, const float* __restrict__ sc1,
    const float4* __restrict__ pts4, const int* __restrict__ starts,
    float* __restrict__ out)
{
    int lane = threadIdx.x & 63;
    int wv   = threadIdx.x >> 6;
    int qid  = blockIdx.x * 2 + wv;          // 0..16383
    int side = qid >> 13, q = qid & (M_Q - 1);
    const float* sc = side ? sc1 : sc0;

    float ax = sc[q * 3], ay = sc[q * 3 + 1], az = sc[q * 3 + 2];
    float a2 = rn_add(rn_add(rn_mul(ax, ax), rn_mul(ay, ay)), rn_mul(az, az));
    const int* st = starts + side * NC;

    float d1 = INF_F, d2 = INF_F;            // per-lane privates (disjoint pts)
    int   i1 = MAXI,  i2 = MAXI;

    // scan points [s0+sub, s1) stride `step`, 2-deep prefetch; ONE load stream
    auto scan_range = [&](int s0, int s1, int sub, int step) {
        int j = s0 + sub;
        if (j >= s1) return;
        float4 p = pts4[j];
        for (j += step; j < s1; j += step) {
            float4 pn = pts4[j];
            float b2 = rn_add(rn_add(rn_mul(p.x, p.x), rn_mul(p.y, p.y)),
                              rn_mul(p.z, p.z));
            float dot = __builtin_fmaf(az, p.z,
                         __builtin_fmaf(ay, p.y, rn_mul(ax, p.x)));
            float dd = __builtin_fmaf(-2.0f, dot, rn_add(a2, b2));
            ins_lex(dd, __float_as_int(p.w), d1, i1, d2, i2);
            p = pn;
        }
        float b2 = rn_add(rn_add(rn_mul(p.x, p.x), rn_mul(p.y, p.y)),
                          rn_mul(p.z, p.z));
        float dot = __builtin_fmaf(az, p.z,
                     __builtin_fmaf(ay, p.y, rn_mul(ax, p.x)));
        float dd = __builtin_fmaf(-2.0f, dot, rn_add(a2, b2));
        ins_lex(dd, __float_as_int(p.w), d1, i1, d2, i2);
    };

    // measured density-adaptive initial radius from the query cell's count
    int cx = cellco(ax), cy = cellco(ay), cz = cellco(az);
    int cc = (cz * GS + cy) * GS + cx;
    int n0 = st[cc + 1] - st[cc];            // wave-uniform probe (r20: best)
    float R = (n0 >= 6) ? 0.12f : ((n0 >= 2) ? 0.19f : 0.30f);

    int pxlo = 0, pxhi = -1, pylo = 0, pyhi = -1, pzlo = 0, pzhi = -1; // empty
#pragma unroll 1
    for (int round = 0; round < 16; ++round) {
        int xlo = cellco(ax - R), xhi = cellco(ax + R);
        int ylo = cellco(ay - R), yhi = cellco(ay + R);
        int zlo = cellco(az - R), zhi = cellco(az + R);
        int sy = yhi - ylo + 1, sz = zhi - zlo + 1;
        int rows = sy * sz;
        int SUB = 64 / rows; if (SUB < 1) SUB = 1;   // lanes per row
        int slots = rows * SUB;
        for (int k = lane; k < slots; k += 64) {
            int row = k / SUB, sub = k - row * SUB;
            int dz = row / sy, dy = row - dz * sy;
            int zz = zlo + dz, yy = ylo + dy;
            int rowbase = (zz * GS + yy) * GS;
            bool inPrev = (zz >= pzlo && zz <= pzhi && yy >= pylo && yy <= pyhi);
            if (inPrev) {
                // only the two x-subranges outside the previous box are new
                scan_range(st[rowbase + xlo], st[rowbase + pxlo], sub, SUB);
                scan_range(st[rowbase + pxhi + 1], st[rowbase + xhi + 1], sub, SUB);
            } else {
                scan_range(st[rowbase + xlo], st[rowbase + xhi + 1], sub, SUB);
            }
        }
        pxlo = xlo; pxhi = xhi; pylo = ylo; pyhi = yhi; pzlo = zlo; pzhi = zhi;

        // stop bound from the scanned-box faces (>= R on non-edge axes)
        float bnd = INF_F;
        if (xlo > 0)      bnd = fminf(bnd, ax - (LOC + xlo * CWID));
        if (xhi < GS - 1) bnd = fminf(bnd, (LOC + (xhi + 1) * CWID) - ax);
        if (ylo > 0)      bnd = fminf(bnd, ay - (LOC + ylo * CWID));
        if (yhi < GS - 1) bnd = fminf(bnd, (LOC + (yhi + 1) * CWID) - ay);
        if (zlo > 0)      bnd = fminf(bnd, az - (LOC + zlo * CWID));
        if (zhi < GS - 1) bnd = fminf(bnd, (LOC + (zhi + 1) * CWID) - az);
        if (bnd == INF_F) break;                 // whole grid scanned

        // cheap exact 2nd-smallest VALUE across lanes for the stop test
        float p1 = d1, p2 = d2;
#pragma unroll
        for (int mk = 1; mk < 64; mk <<= 1) {
            float o1 = __shfl_xor(p1, mk);
            float o2 = __shfl_xor(p2, mk);
            vpair_merge(p1, p2, o1, o2);
        }
        if (p2 < bnd * bnd - MARG) break;        // rigorous exact stop

        // certified-radius jump: sqrt(p2+MARG) is exactly the radius whose
        // box certifies the current top-2; guarantees <=1 more content round.
        if (p2 < INF_F) {
            float Rj = sqrtf(p2 + MARG) * 1.0001f + 1e-4f;
            R = fmaxf(Rj, R * 1.02f);            // monotone growth
        } else {
            R *= 2.0f;                           // empty so far: double
        }
    }

    // ---- one exact lex butterfly (privates pure; disjoint point sets) ----
    float t1 = d1, t2 = d2; int u1 = i1, u2 = i2;
#pragma unroll
    for (int mk = 1; mk < 64; mk <<= 1) {
        float o1 = __shfl_xor(t1, mk); int p1 = __shfl_xor(u1, mk);
        float o2 = __shfl_xor(t2, mk); int p2 = __shfl_xor(u2, mk);
        ins_lex(o1, p1, t1, u1, t2, u2);
        ins_lex2(o2, p2, t2, u2);
    }

    // fused gather: result uniform across the wave; 64 lanes x float4 = row
    const float* feats = side ? tgt : src;
    const float4* sp = (const float4*)(feats + (size_t)u2 * C_F);
    float4* dp = (float4*)(out + (size_t)qid * C_F);
    dp[lane] = sp[lane];
}

extern "C" void kernel_launch(void* const* d_in, const int* in_sizes, int n_in,
                              void* d_out, int out_size, void* d_ws, size_t ws_size,
                              hipStream_t stream) {
    const float* src  = (const float*)d_in[0];
    const float* tgt  = (const float*)d_in[1];
    const float* c0   = (const float*)d_in[2];  // src_coords   (N,3)
    const float* c1   = (const float*)d_in[3];  // tgt_coords   (N,3)
    const float* sh0  = (const float*)d_in[4];  // src_shortcut (M,3)
    const float* sh1  = (const float*)d_in[5];  // tgt_shortcut (M,3)
    float* out = (float*)d_out;

    char* w = (char*)d_ws;
    float4* pts4   = (float4*)(w);                       // 1,048,576
    int*    cid    = (int*)(w + 1048576);                //   262,144
    int*    counts = (int*)(w + 1310720);                //   262,144
    int*    starts = (int*)(w + 1572864);                //   262,148 (65537)
    int*    bsum   = (int*)(w + 1835012);                //     1,024

    hipMemsetAsync(counts, 0, (size_t)TOTP * sizeof(int), stream);

    hipLaunchKernelGGL(build_cells, dim3(TOTP / 256), dim3(256), 0, stream,
                       c0, c1, counts, cid);
    hipLaunchKernelGGL(scan1, dim3(TOTP / 256), dim3(256), 0, stream,
                       counts, starts, bsum);
    hipLaunchKernelGGL(scan23, dim3(TOTP / 256), dim3(256), 0, stream,
                       starts, bsum);
    hipLaunchKernelGGL(scatter, dim3(TOTP / 256), dim3(256), 0, stream,
                       c0, c1, cid, starts, counts, pts4);
    hipLaunchKernelGGL(query2nn, dim3(TOTQ / 2), dim3(128), 0, stream,
                       src, tgt, sh0, sh1, pts4, starts, out);
}